// Round 17
// baseline (216.613 us; speedup 1.0000x reference)
//
#include <hip/hip_runtime.h>
#include <hip/hip_bf16.h>
#include <math.h>

#define NB   16
#define C1   256
#define C2   256
#define NK   5
#define NEXP (C2 * NK)   // 1280
#define HW   4096

typedef __attribute__((ext_vector_type(8))) short bf16x8;
typedef __attribute__((ext_vector_type(4))) float f32x4;

#define GLOAD_LDS16(g, l) __builtin_amdgcn_global_load_lds( \
    (const __attribute__((address_space(1))) void*)(g), \
    (__attribute__((address_space(3))) void*)(l), 16, 0, 0)

__device__ __forceinline__ unsigned short bfbits(float v) {
    return __builtin_bit_cast(unsigned short, __float2bfloat16(v));
}
__device__ __forceinline__ float bflo(unsigned u) { return __uint_as_float(u << 16); }
__device__ __forceinline__ float bfhi(unsigned u) { return __uint_as_float(u & 0xffff0000u); }

// lgkm-only barrier: ds ops drained, VMEM stays in flight (T4)
#define LGKM_BARRIER() do { \
    asm volatile("s_waitcnt lgkmcnt(0)" ::: "memory"); \
    __builtin_amdgcn_sched_barrier(0); \
    __builtin_amdgcn_s_barrier(); } while (0)

// ---------------------------------------------------------------------------
__global__ void weff_kernel(const float* __restrict__ w_path, float* __restrict__ weff) {
    int idx = blockIdx.x * 256 + threadIdx.x;
    if (idx >= NK * C2 * 9) return;
    float s = 0.f;
    #pragma unroll
    for (int p = 0; p < 3; ++p)
        s += w_path[(long)p * NK * C2 * 9 + idx];
    weff[idx] = s;
}

__global__ void cvt_bf16_kernel(const float* __restrict__ in, __hip_bfloat16* __restrict__ out, int n) {
    int i = blockIdx.x * 256 + threadIdx.x;
    if (i < n) out[i] = __float2bfloat16(in[i]);
}

// ---------------------------------------------------------------------------
// N-streaming weight-stationary MFMA GEMM (R13/R16-proven config — frozen).
// ---------------------------------------------------------------------------
template <int NCH, bool FP32B, bool OUT_BF16>
__global__ __launch_bounds__(512, 2)
void nstream_gemm_kernel(const __hip_bfloat16* __restrict__ A,   // [M][256] bf16
                         const void* __restrict__ B_all,         // [z][256][4096]
                         void* __restrict__ C_all,
                         long bStrideB, long bStrideC, int bOffB, int bOffC,
                         const float* __restrict__ bn_gamma, const float* __restrict__ bn_beta,
                         const float* __restrict__ bn_mean, const float* __restrict__ bn_var) {
    constexpr int KK = 256, NN = 4096;
    __shared__ __align__(16) char Bs[2][64 * 512];   // 2 x 32 KB
    const int z  = blockIdx.z;
    const int nBase = blockIdx.x * (64 * NCH);
    const int m0 = blockIdx.y * 256;
    const int t  = threadIdx.x;
    const int lane = t & 63;
    const int wv = t >> 6;            // 0..7
    const int lr = lane & 15, lg = lane >> 4;

    // ---- W fragments, register-resident
    bf16x8 af[2][8];
    const __hip_bfloat16* wp = A + (long)(m0 + wv * 32 + lr) * KK + lg * 8;
    #pragma unroll
    for (int s = 0; s < 2; ++s)
        #pragma unroll
        for (int ks = 0; ks < 8; ++ks)
            af[s][ks] = *(const bf16x8*)(wp + (long)s * 16 * KK + ks * 32);

    // ---- BN params hoisted
    float scl[2], mnv[2], btv[2];
    if constexpr (!OUT_BF16) {
        #pragma unroll
        for (int s = 0; s < 2; ++s) {
            const int m = m0 + wv * 32 + s * 16 + lr;
            scl[s] = bn_gamma[m] * rsqrtf(bn_var[m] + 1e-5f);
            mnv[s] = bn_mean[m];
            btv[s] = bn_beta[m];
        }
    }

    // ---- staging ids
    const int sn = t & 63;
    const int kb = (t >> 6) * 32;
    const int key = sn & 31;
    const char* Bbase = (const char*)B_all + (long)(bOffB + z) * bStrideB * (FP32B ? 4 : 2);

    float    fr[32];
    unsigned hr[32];

    auto issueB = [&](int ci) {
        const int nc = nBase + ci * 64 + sn;
        #pragma unroll
        for (int gq = 0; gq < 2; ++gq) {
            if constexpr (FP32B) {
                const float* p = (const float*)Bbase + (long)(kb + gq * 16) * NN + nc;
                #pragma unroll
                for (int i = 0; i < 16; ++i) fr[gq * 16 + i] = p[(long)i * NN];
            } else {
                const unsigned short* p = (const unsigned short*)Bbase + (long)(kb + gq * 16) * NN + nc;
                #pragma unroll
                for (int i = 0; i < 16; ++i) hr[gq * 16 + i] = p[(long)i * NN];
            }
        }
    };
    auto writeB = [&](int ci) {
        char* buf = Bs[ci & 1];
        #pragma unroll
        for (int gq = 0; gq < 2; ++gq) {
            unsigned u[8];
            #pragma unroll
            for (int i = 0; i < 8; ++i) {
                if constexpr (FP32B)
                    u[i] = (unsigned)bfbits(fr[gq * 16 + 2 * i]) |
                           ((unsigned)bfbits(fr[gq * 16 + 2 * i + 1]) << 16);
                else
                    u[i] = (hr[gq * 16 + 2 * i] & 0xffffu) | (hr[gq * 16 + 2 * i + 1] << 16);
            }
            const int ch0 = (kb >> 3) + gq * 2;
            *(uint4*)(buf + sn * 512 + ((ch0 ^ key) * 16))       = *(uint4*)&u[0];
            *(uint4*)(buf + sn * 512 + (((ch0 + 1) ^ key) * 16)) = *(uint4*)&u[4];
        }
    };

    // ---- prologue
    issueB(0);
    writeB(0);
    LGKM_BARRIER();

    #pragma unroll
    for (int ci = 0; ci < NCH; ++ci) {
        if (ci + 1 < NCH) {
            issueB(ci + 1);                          // issue-early (T14)
            __builtin_amdgcn_sched_barrier(0);
        }
        char* buf = Bs[ci & 1];

        f32x4 acc[2][4];
        #pragma unroll
        for (int s = 0; s < 2; ++s)
            #pragma unroll
            for (int j = 0; j < 4; ++j)
                acc[s][j] = (f32x4){0.f, 0.f, 0.f, 0.f};

        __builtin_amdgcn_s_setprio(1);               // T5
        #pragma unroll
        for (int ks = 0; ks < 8; ++ks) {
            #pragma unroll
            for (int j = 0; j < 4; ++j) {
                const int n = j * 16 + lr;
                bf16x8 bfr = *(const bf16x8*)(buf + n * 512 + (((ks * 4 + lg) ^ (n & 31)) * 16));
                acc[0][j] = __builtin_amdgcn_mfma_f32_16x16x32_bf16(bfr, af[0][ks], acc[0][j], 0, 0, 0);
                acc[1][j] = __builtin_amdgcn_mfma_f32_16x16x32_bf16(bfr, af[1][ks], acc[1][j], 0, 0, 0);
            }
        }
        __builtin_amdgcn_s_setprio(0);

        const int ncb = nBase + ci * 64;
        if constexpr (OUT_BF16) {
            if (ci + 1 < NCH) writeB(ci + 1);
            __hip_bfloat16* C = (__hip_bfloat16*)C_all + (long)(bOffC + z) * bStrideC;
            #pragma unroll
            for (int s = 0; s < 2; ++s) {
                const int m = m0 + wv * 32 + s * 16 + lr;
                #pragma unroll
                for (int j = 0; j < 4; ++j) {
                    const long n = ncb + j * 16 + lg * 4;
                    short4 sv;
                    sv.x = (short)bfbits(acc[s][j][0]);
                    sv.y = (short)bfbits(acc[s][j][1]);
                    sv.z = (short)bfbits(acc[s][j][2]);
                    sv.w = (short)bfbits(acc[s][j][3]);
                    *(short4*)(C + (long)m * NN + n) = sv;
                }
            }
            if (ci + 1 < NCH) LGKM_BARRIER();
        } else {
            // LDS-staged coalesced fp32 epilogue (R13)
            float* C = (float*)C_all + (long)(bOffC + z) * bStrideC;
            LGKM_BARRIER();
            #pragma unroll
            for (int h = 0; h < 2; ++h) {
                if ((wv >> 2) == h) {
                    #pragma unroll
                    for (int s = 0; s < 2; ++s) {
                        const int mrel = (wv & 3) * 32 + s * 16 + lr;
                        const int kx = (mrel & 7) << 4;
                        #pragma unroll
                        for (int j = 0; j < 4; ++j) {
                            const int nb = j * 64 + lg * 16;
                            float4 v;
                            float t0 = (acc[s][j][0] - mnv[s]) * scl[s] + btv[s];
                            float t1 = (acc[s][j][1] - mnv[s]) * scl[s] + btv[s];
                            float t2 = (acc[s][j][2] - mnv[s]) * scl[s] + btv[s];
                            float t3 = (acc[s][j][3] - mnv[s]) * scl[s] + btv[s];
                            v.x = t0 / (1.0f + __expf(-t0));
                            v.y = t1 / (1.0f + __expf(-t1));
                            v.z = t2 / (1.0f + __expf(-t2));
                            v.w = t3 / (1.0f + __expf(-t3));
                            *(float4*)(buf + mrel * 256 + (nb ^ kx)) = v;
                        }
                    }
                }
                LGKM_BARRIER();
                #pragma unroll
                for (int i = 0; i < 4; ++i) {
                    const int p = i * 8192 + t * 16;
                    const int mrel = p >> 8;
                    const int w = p & 255;
                    uint4 v = *(uint4*)(buf + mrel * 256 + (w ^ ((mrel & 7) << 4)));
                    *(uint4*)((char*)(C + (long)(m0 + h * 128 + mrel) * NN + ncb) + w) = v;
                }
                LGKM_BARRIER();
            }
            if (ci + 1 < NCH) {
                writeB(ci + 1);
                LGKM_BARRIER();
            }
        }
    }
}

// ---------------------------------------------------------------------------
// Stage 2 v4: half-plane blocks (32 output rows, 34 staged rows, 21.8 KB LDS,
// 256 thr -> 7 blocks/CU for HBM-latency TLP) + v3's b32-pair column reads.
// Edge handling: 2-row masks (topEdge/botEdge) instead of guard rows.
// ---------------------------------------------------------------------------
__global__ __launch_bounds__(256)
void shift_dw_kernel(const __hip_bfloat16* __restrict__ xexp,  // [z][1280][64][64]
                     const float* __restrict__ weff,           // [5][256][9]
                     __hip_bfloat16* __restrict__ merged) {    // [z][256][4096]
    __shared__ __align__(16) __hip_bfloat16 sd[NK * 34 * 64];  // 21760 B
    const int t  = threadIdx.x;
    const int r0 = blockIdx.x * 32;        // 0 or 32
    const int c  = blockIdx.y;
    const int z  = blockIdx.z;
    const int shifts[NK] = {-4, -1, 2, 5, 8};
    const __hip_bfloat16* base = xexp + ((long)z * NEXP + (long)c * NK) * HW;

    // stage 34 rolled rows x 5 planes via global_load_lds (linear dest)
    #pragma unroll
    for (int i = 0; i < 6; ++i) {
        const int idx = t + i * 256;       // 16B chunk index, 1360 total
        if (idx < NK * 34 * 8) {
            const int k   = idx / 272;     // 34*8
            const int rem = idx - k * 272;
            const int rr  = rem >> 3, ch = (rem & 7) * 8;
            const int grow = (r0 - 1 + rr - shifts[k]) & 63;
            GLOAD_LDS16(base + (long)k * HW + grow * 64 + ch, (char*)sd + idx * 16);
        }
    }
    __syncthreads();

    const int pairi = t & 31;
    const int j2 = pairi * 2;              // output cols j2, j2+1
    const int ty = t >> 5;                 // 0..7
    const int pbase = ty * 4;              // slot of row (r0+ty*4)-1
    const bool topEdge = (r0 == 0)  && (ty == 0);   // slot 0 = row -1
    const bool botEdge = (r0 == 32) && (ty == 7);   // slot 33 = row 64

    f32x4 acc[2];
    acc[0] = (f32x4){0.f, 0.f, 0.f, 0.f};
    acc[1] = (f32x4){0.f, 0.f, 0.f, 0.f};

    #pragma unroll
    for (int k = 0; k < NK; ++k) {
        const int s = shifts[k];
        const float* wpk = &weff[((long)k * C2 + c) * 9];
        float wA[9], wB[9];
        #pragma unroll
        for (int i = 0; i < 9; ++i) { wA[i] = wpk[i]; wB[i] = wA[i]; }
        if (j2 == 0)      { wA[0] = 0.f; wA[3] = 0.f; wA[6] = 0.f; }
        if (j2 + 1 == 63) { wB[2] = 0.f; wB[5] = 0.f; wB[8] = 0.f; }
        const int cin = (j2 - 1 - s) & 63;   // input col of leftmost tap
        const __hip_bfloat16* sdk = sd + k * (34 * 64);

        float V0[4], V1[4], V2[4], V3[4];
        auto LDR = [&](int rs, int slot) {
            const __hip_bfloat16* rp = sdk + (pbase + rs) * 64;
            if ((cin & 1) == 0) {            // taps start on even col
                unsigned a = *(const unsigned*)(rp + cin);
                unsigned b = *(const unsigned*)(rp + ((cin + 2) & 63));
                V0[slot] = bflo(a); V1[slot] = bfhi(a);
                V2[slot] = bflo(b); V3[slot] = bfhi(b);
            } else {                          // taps start on odd col
                unsigned a = *(const unsigned*)(rp + (cin & 62));
                unsigned b = *(const unsigned*)(rp + ((cin + 1) & 63));
                unsigned d = *(const unsigned*)(rp + ((cin + 3) & 63));
                V0[slot] = bfhi(a);
                V1[slot] = bflo(b); V2[slot] = bfhi(b);
                V3[slot] = bflo(d);
            }
        };

        LDR(0, 0); LDR(1, 1); LDR(2, 2); LDR(3, 3);
        if (topEdge) { V0[0] = 0.f; V1[0] = 0.f; V2[0] = 0.f; V3[0] = 0.f; }
        #pragma unroll
        for (int pr = 0; pr < 2; ++pr) {
            #pragma unroll
            for (int u = 0; u < 3; ++u) {
                const int iA = (2 * pr + u) & 3;
                const int iB = (2 * pr + u + 1) & 3;
                acc[pr][0] += wA[u*3] * V0[iA] + wA[u*3+1] * V1[iA] + wA[u*3+2] * V2[iA];
                acc[pr][1] += wB[u*3] * V1[iA] + wB[u*3+1] * V2[iA] + wB[u*3+2] * V3[iA];
                acc[pr][2] += wA[u*3] * V0[iB] + wA[u*3+1] * V1[iB] + wA[u*3+2] * V2[iB];
                acc[pr][3] += wB[u*3] * V1[iB] + wB[u*3+1] * V2[iB] + wB[u*3+2] * V3[iB];
            }
            if (pr == 0) {
                LDR(4, 0); LDR(5, 1);
                if (botEdge) { V0[1] = 0.f; V1[1] = 0.f; V2[1] = 0.f; V3[1] = 0.f; }
            }
        }
    }

    __hip_bfloat16* out = merged + ((long)z * C2 + c) * HW + (long)(r0 + pbase) * 64 + j2;
    #pragma unroll
    for (int pr = 0; pr < 2; ++pr) {
        unsigned ua = (unsigned)bfbits(acc[pr][0]) | ((unsigned)bfbits(acc[pr][1]) << 16);
        unsigned ub = (unsigned)bfbits(acc[pr][2]) | ((unsigned)bfbits(acc[pr][3]) << 16);
        *(unsigned*)(out + (long)(2 * pr) * 64)     = ua;
        *(unsigned*)(out + (long)(2 * pr + 1) * 64) = ub;
    }
}

// ---------------------------------------------------------------------------
extern "C" void kernel_launch(void* const* d_in, const int* in_sizes, int n_in,
                              void* d_out, int out_size, void* d_ws, size_t ws_size,
                              hipStream_t stream) {
    const float* x        = (const float*)d_in[0];
    const float* w_expand = (const float*)d_in[1];
    const float* w_path   = (const float*)d_in[2];
    const float* w_mix    = (const float*)d_in[3];
    const float* bn_gamma = (const float*)d_in[4];
    const float* bn_beta  = (const float*)d_in[5];
    const float* bn_mean  = (const float*)d_in[6];
    const float* bn_var   = (const float*)d_in[7];

    char* ws = (char*)d_ws;
    float* weff             = (float*)ws;
    __hip_bfloat16* wexp_bf = (__hip_bfloat16*)(ws + 65536);
    __hip_bfloat16* wmix_bf = (__hip_bfloat16*)(ws + 65536 + 655360);
    const size_t head = 1 << 20;

    const size_t xe_per = (size_t)NEXP * HW * 2;   // 10 MB
    const size_t mg_per = (size_t)C2 * HW * 2;     // 2 MB
    const size_t per_b = xe_per + mg_per;          // 12 MB

    int g = 1;
    if (ws_size > head + per_b) {
        size_t fit = (ws_size - head) / per_b;
        g = (int)(fit < NB ? fit : NB);
        if (g < 1) g = 1;
    }

    char* p = ws + head;
    __hip_bfloat16* xexp   = (__hip_bfloat16*)p; p += (size_t)g * xe_per;
    __hip_bfloat16* merged = (__hip_bfloat16*)p;

    weff_kernel<<<(NK * C2 * 9 + 255) / 256, 256, 0, stream>>>(w_path, weff);
    cvt_bf16_kernel<<<(NEXP * C1 + 255) / 256, 256, 0, stream>>>(w_expand, wexp_bf, NEXP * C1);
    cvt_bf16_kernel<<<(C2 * C2 + 255) / 256, 256, 0, stream>>>(w_mix, wmix_bf, C2 * C2);

    for (int b0 = 0; b0 < NB; b0 += g) {
        int gb = (NB - b0) < g ? (NB - b0) : g;
        // expand (frozen R13/R16 config): NCH=4, plain grid, short4 epilogue
        nstream_gemm_kernel<4, true, true><<<dim3(HW / 256, NEXP / 256, gb), 512, 0, stream>>>(
            wexp_bf, x, xexp,
            (long)C1 * HW, (long)NEXP * HW, b0, 0,
            nullptr, nullptr, nullptr, nullptr);
        // shift_dw v4: half-plane, 7 blocks/CU
        shift_dw_kernel<<<dim3(2, C2, gb), 256, 0, stream>>>(xexp, weff, merged);
        // mix: NCH=2, LDS-staged fp32 epilogue
        nstream_gemm_kernel<2, false, false><<<dim3(HW / 128, 1, gb), 512, 0, stream>>>(
            wmix_bf, merged, d_out,
            (long)C2 * HW, (long)C2 * HW, 0, b0,
            bn_gamma, bn_beta, bn_mean, bn_var);
    }
}

// Round 18
// 201.257 us; speedup vs baseline: 1.0763x; 1.0763x over previous
//
#include <hip/hip_runtime.h>
#include <hip/hip_bf16.h>
#include <math.h>

#define NB   16
#define C1   256
#define C2   256
#define NK   5
#define NEXP (C2 * NK)   // 1280
#define HW   4096

typedef __attribute__((ext_vector_type(8))) short bf16x8;
typedef __attribute__((ext_vector_type(4))) float f32x4;

#define GLOAD_LDS16(g, l) __builtin_amdgcn_global_load_lds( \
    (const __attribute__((address_space(1))) void*)(g), \
    (__attribute__((address_space(3))) void*)(l), 16, 0, 0)

__device__ __forceinline__ unsigned short bfbits(float v) {
    return __builtin_bit_cast(unsigned short, __float2bfloat16(v));
}
__device__ __forceinline__ float bflo(unsigned u) { return __uint_as_float(u << 16); }
__device__ __forceinline__ float bfhi(unsigned u) { return __uint_as_float(u & 0xffff0000u); }

// lgkm-only barrier: ds ops drained, VMEM stays in flight (T4)
#define LGKM_BARRIER() do { \
    asm volatile("s_waitcnt lgkmcnt(0)" ::: "memory"); \
    __builtin_amdgcn_sched_barrier(0); \
    __builtin_amdgcn_s_barrier(); } while (0)

// ---------------------------------------------------------------------------
__global__ void weff_kernel(const float* __restrict__ w_path, float* __restrict__ weff) {
    int idx = blockIdx.x * 256 + threadIdx.x;
    if (idx >= NK * C2 * 9) return;
    float s = 0.f;
    #pragma unroll
    for (int p = 0; p < 3; ++p)
        s += w_path[(long)p * NK * C2 * 9 + idx];
    weff[idx] = s;
}

__global__ void cvt_bf16_kernel(const float* __restrict__ in, __hip_bfloat16* __restrict__ out, int n) {
    int i = blockIdx.x * 256 + threadIdx.x;
    if (i < n) out[i] = __float2bfloat16(in[i]);
}

// ---------------------------------------------------------------------------
// N-streaming weight-stationary MFMA GEMM (R13/R16-proven config — frozen).
// ---------------------------------------------------------------------------
template <int NCH, bool FP32B, bool OUT_BF16>
__global__ __launch_bounds__(512, 2)
void nstream_gemm_kernel(const __hip_bfloat16* __restrict__ A,   // [M][256] bf16
                         const void* __restrict__ B_all,         // [z][256][4096]
                         void* __restrict__ C_all,
                         long bStrideB, long bStrideC, int bOffB, int bOffC,
                         const float* __restrict__ bn_gamma, const float* __restrict__ bn_beta,
                         const float* __restrict__ bn_mean, const float* __restrict__ bn_var) {
    constexpr int KK = 256, NN = 4096;
    __shared__ __align__(16) char Bs[2][64 * 512];   // 2 x 32 KB
    const int z  = blockIdx.z;
    const int nBase = blockIdx.x * (64 * NCH);
    const int m0 = blockIdx.y * 256;
    const int t  = threadIdx.x;
    const int lane = t & 63;
    const int wv = t >> 6;            // 0..7
    const int lr = lane & 15, lg = lane >> 4;

    // ---- W fragments, register-resident
    bf16x8 af[2][8];
    const __hip_bfloat16* wp = A + (long)(m0 + wv * 32 + lr) * KK + lg * 8;
    #pragma unroll
    for (int s = 0; s < 2; ++s)
        #pragma unroll
        for (int ks = 0; ks < 8; ++ks)
            af[s][ks] = *(const bf16x8*)(wp + (long)s * 16 * KK + ks * 32);

    // ---- BN params hoisted
    float scl[2], mnv[2], btv[2];
    if constexpr (!OUT_BF16) {
        #pragma unroll
        for (int s = 0; s < 2; ++s) {
            const int m = m0 + wv * 32 + s * 16 + lr;
            scl[s] = bn_gamma[m] * rsqrtf(bn_var[m] + 1e-5f);
            mnv[s] = bn_mean[m];
            btv[s] = bn_beta[m];
        }
    }

    // ---- staging ids
    const int sn = t & 63;
    const int kb = (t >> 6) * 32;
    const int key = sn & 31;
    const char* Bbase = (const char*)B_all + (long)(bOffB + z) * bStrideB * (FP32B ? 4 : 2);

    float    fr[32];
    unsigned hr[32];

    auto issueB = [&](int ci) {
        const int nc = nBase + ci * 64 + sn;
        #pragma unroll
        for (int gq = 0; gq < 2; ++gq) {
            if constexpr (FP32B) {
                const float* p = (const float*)Bbase + (long)(kb + gq * 16) * NN + nc;
                #pragma unroll
                for (int i = 0; i < 16; ++i) fr[gq * 16 + i] = p[(long)i * NN];
            } else {
                const unsigned short* p = (const unsigned short*)Bbase + (long)(kb + gq * 16) * NN + nc;
                #pragma unroll
                for (int i = 0; i < 16; ++i) hr[gq * 16 + i] = p[(long)i * NN];
            }
        }
    };
    auto writeB = [&](int ci) {
        char* buf = Bs[ci & 1];
        #pragma unroll
        for (int gq = 0; gq < 2; ++gq) {
            unsigned u[8];
            #pragma unroll
            for (int i = 0; i < 8; ++i) {
                if constexpr (FP32B)
                    u[i] = (unsigned)bfbits(fr[gq * 16 + 2 * i]) |
                           ((unsigned)bfbits(fr[gq * 16 + 2 * i + 1]) << 16);
                else
                    u[i] = (hr[gq * 16 + 2 * i] & 0xffffu) | (hr[gq * 16 + 2 * i + 1] << 16);
            }
            const int ch0 = (kb >> 3) + gq * 2;
            *(uint4*)(buf + sn * 512 + ((ch0 ^ key) * 16))       = *(uint4*)&u[0];
            *(uint4*)(buf + sn * 512 + (((ch0 + 1) ^ key) * 16)) = *(uint4*)&u[4];
        }
    };

    // ---- prologue
    issueB(0);
    writeB(0);
    LGKM_BARRIER();

    #pragma unroll
    for (int ci = 0; ci < NCH; ++ci) {
        if (ci + 1 < NCH) {
            issueB(ci + 1);                          // issue-early (T14)
            __builtin_amdgcn_sched_barrier(0);
        }
        char* buf = Bs[ci & 1];

        f32x4 acc[2][4];
        #pragma unroll
        for (int s = 0; s < 2; ++s)
            #pragma unroll
            for (int j = 0; j < 4; ++j)
                acc[s][j] = (f32x4){0.f, 0.f, 0.f, 0.f};

        __builtin_amdgcn_s_setprio(1);               // T5
        #pragma unroll
        for (int ks = 0; ks < 8; ++ks) {
            #pragma unroll
            for (int j = 0; j < 4; ++j) {
                const int n = j * 16 + lr;
                bf16x8 bfr = *(const bf16x8*)(buf + n * 512 + (((ks * 4 + lg) ^ (n & 31)) * 16));
                acc[0][j] = __builtin_amdgcn_mfma_f32_16x16x32_bf16(bfr, af[0][ks], acc[0][j], 0, 0, 0);
                acc[1][j] = __builtin_amdgcn_mfma_f32_16x16x32_bf16(bfr, af[1][ks], acc[1][j], 0, 0, 0);
            }
        }
        __builtin_amdgcn_s_setprio(0);

        const int ncb = nBase + ci * 64;
        if constexpr (OUT_BF16) {
            if (ci + 1 < NCH) writeB(ci + 1);
            __hip_bfloat16* C = (__hip_bfloat16*)C_all + (long)(bOffC + z) * bStrideC;
            #pragma unroll
            for (int s = 0; s < 2; ++s) {
                const int m = m0 + wv * 32 + s * 16 + lr;
                #pragma unroll
                for (int j = 0; j < 4; ++j) {
                    const long n = ncb + j * 16 + lg * 4;
                    short4 sv;
                    sv.x = (short)bfbits(acc[s][j][0]);
                    sv.y = (short)bfbits(acc[s][j][1]);
                    sv.z = (short)bfbits(acc[s][j][2]);
                    sv.w = (short)bfbits(acc[s][j][3]);
                    *(short4*)(C + (long)m * NN + n) = sv;
                }
            }
            if (ci + 1 < NCH) LGKM_BARRIER();
        } else {
            // LDS-staged coalesced fp32 epilogue (R13)
            float* C = (float*)C_all + (long)(bOffC + z) * bStrideC;
            LGKM_BARRIER();
            #pragma unroll
            for (int h = 0; h < 2; ++h) {
                if ((wv >> 2) == h) {
                    #pragma unroll
                    for (int s = 0; s < 2; ++s) {
                        const int mrel = (wv & 3) * 32 + s * 16 + lr;
                        const int kx = (mrel & 7) << 4;
                        #pragma unroll
                        for (int j = 0; j < 4; ++j) {
                            const int nb = j * 64 + lg * 16;
                            float4 v;
                            float t0 = (acc[s][j][0] - mnv[s]) * scl[s] + btv[s];
                            float t1 = (acc[s][j][1] - mnv[s]) * scl[s] + btv[s];
                            float t2 = (acc[s][j][2] - mnv[s]) * scl[s] + btv[s];
                            float t3 = (acc[s][j][3] - mnv[s]) * scl[s] + btv[s];
                            v.x = t0 / (1.0f + __expf(-t0));
                            v.y = t1 / (1.0f + __expf(-t1));
                            v.z = t2 / (1.0f + __expf(-t2));
                            v.w = t3 / (1.0f + __expf(-t3));
                            *(float4*)(buf + mrel * 256 + (nb ^ kx)) = v;
                        }
                    }
                }
                LGKM_BARRIER();
                #pragma unroll
                for (int i = 0; i < 4; ++i) {
                    const int p = i * 8192 + t * 16;
                    const int mrel = p >> 8;
                    const int w = p & 255;
                    uint4 v = *(uint4*)(buf + mrel * 256 + (w ^ ((mrel & 7) << 4)));
                    *(uint4*)((char*)(C + (long)(m0 + h * 128 + mrel) * NN + ncb) + w) = v;
                }
                LGKM_BARRIER();
            }
            if (ci + 1 < NCH) {
                writeB(ci + 1);
                LGKM_BARRIER();
            }
        }
    }
}

// ---------------------------------------------------------------------------
// Stage 2 v3 (R16-proven): full 64-row plane per block, zero-guard rows,
// 2 output cols/thread -> aligned b32 pair reads. 512 thr.
// ---------------------------------------------------------------------------
__global__ __launch_bounds__(512)
void shift_dw_kernel(const __hip_bfloat16* __restrict__ xexp,  // [z][1280][64][64]
                     const float* __restrict__ weff,           // [5][256][9]
                     __hip_bfloat16* __restrict__ merged) {    // [z][256][4096]
    __shared__ __align__(16) __hip_bfloat16 sd[NK * 66 * 64];  // 42240 B
    const int t = threadIdx.x;
    const int c = blockIdx.x;
    const int z = blockIdx.y;
    const int shifts[NK] = {-4, -1, 2, 5, 8};
    const __hip_bfloat16* base = xexp + ((long)z * NEXP + (long)c * NK) * HW;

    // zero guard rows: slots 0 and 65 of each plane
    if (t < 80) {
        const int k = t >> 4, which = (t >> 3) & 1, ch = (t & 7) * 8;
        bf16x8 zz = {};
        *(bf16x8*)&sd[(k * 66 + which * 65) * 64 + ch] = zz;
    }
    // stage rolled rows: plane k per iteration, dest = uniform + t*16 (linear)
    #pragma unroll
    for (int k = 0; k < NK; ++k) {
        const int r  = t >> 3;             // 0..63
        const int ch = (t & 7) * 8;
        const int grow = (r - shifts[k]) & 63;
        GLOAD_LDS16(base + (long)k * HW + grow * 64 + ch,
                    (char*)sd + (k * 66 + 1) * 128 + t * 16);
    }
    __syncthreads();

    const int pairi = t & 31;
    const int j2 = pairi * 2;
    const int ty = t >> 5;                 // 0..15
    const int pbase = ty * 4;              // first output row

    f32x4 acc[2];
    acc[0] = (f32x4){0.f, 0.f, 0.f, 0.f};
    acc[1] = (f32x4){0.f, 0.f, 0.f, 0.f};

    #pragma unroll
    for (int k = 0; k < NK; ++k) {
        const int s = shifts[k];
        const float* wpk = &weff[((long)k * C2 + c) * 9];
        float wA[9], wB[9];
        #pragma unroll
        for (int i = 0; i < 9; ++i) { wA[i] = wpk[i]; wB[i] = wA[i]; }
        if (j2 == 0)      { wA[0] = 0.f; wA[3] = 0.f; wA[6] = 0.f; }
        if (j2 + 1 == 63) { wB[2] = 0.f; wB[5] = 0.f; wB[8] = 0.f; }
        const int cin = (j2 - 1 - s) & 63;   // input col of leftmost tap
        const __hip_bfloat16* sdk = sd + k * (66 * 64);

        float V0[4], V1[4], V2[4], V3[4];
        auto LDR = [&](int rs, int slot) {
            const __hip_bfloat16* rp = sdk + (pbase + rs) * 64;
            if ((cin & 1) == 0) {            // taps start on even col
                unsigned a = *(const unsigned*)(rp + cin);
                unsigned b = *(const unsigned*)(rp + ((cin + 2) & 63));
                V0[slot] = bflo(a); V1[slot] = bfhi(a);
                V2[slot] = bflo(b); V3[slot] = bfhi(b);
            } else {                          // taps start on odd col
                unsigned a = *(const unsigned*)(rp + (cin & 62));
                unsigned b = *(const unsigned*)(rp + ((cin + 1) & 63));
                unsigned d = *(const unsigned*)(rp + ((cin + 3) & 63));
                V0[slot] = bfhi(a);
                V1[slot] = bflo(b); V2[slot] = bfhi(b);
                V3[slot] = bflo(d);
            }
        };

        LDR(0, 0); LDR(1, 1); LDR(2, 2); LDR(3, 3);
        #pragma unroll
        for (int pr = 0; pr < 2; ++pr) {
            #pragma unroll
            for (int u = 0; u < 3; ++u) {
                const int iA = (2 * pr + u) & 3;
                const int iB = (2 * pr + u + 1) & 3;
                acc[pr][0] += wA[u*3] * V0[iA] + wA[u*3+1] * V1[iA] + wA[u*3+2] * V2[iA];
                acc[pr][1] += wB[u*3] * V1[iA] + wB[u*3+1] * V2[iA] + wB[u*3+2] * V3[iA];
                acc[pr][2] += wA[u*3] * V0[iB] + wA[u*3+1] * V1[iB] + wA[u*3+2] * V2[iB];
                acc[pr][3] += wB[u*3] * V1[iB] + wB[u*3+1] * V2[iB] + wB[u*3+2] * V3[iB];
            }
            if (pr == 0) { LDR(4, 0); LDR(5, 1); }
        }
    }

    __hip_bfloat16* out = merged + ((long)z * C2 + c) * HW + (long)pbase * 64 + j2;
    #pragma unroll
    for (int pr = 0; pr < 2; ++pr) {
        unsigned ua = (unsigned)bfbits(acc[pr][0]) | ((unsigned)bfbits(acc[pr][1]) << 16);
        unsigned ub = (unsigned)bfbits(acc[pr][2]) | ((unsigned)bfbits(acc[pr][3]) << 16);
        *(unsigned*)(out + (long)(2 * pr) * 64)     = ua;
        *(unsigned*)(out + (long)(2 * pr + 1) * 64) = ub;
    }
}

// ---------------------------------------------------------------------------
extern "C" void kernel_launch(void* const* d_in, const int* in_sizes, int n_in,
                              void* d_out, int out_size, void* d_ws, size_t ws_size,
                              hipStream_t stream) {
    const float* x        = (const float*)d_in[0];
    const float* w_expand = (const float*)d_in[1];
    const float* w_path   = (const float*)d_in[2];
    const float* w_mix    = (const float*)d_in[3];
    const float* bn_gamma = (const float*)d_in[4];
    const float* bn_beta  = (const float*)d_in[5];
    const float* bn_mean  = (const float*)d_in[6];
    const float* bn_var   = (const float*)d_in[7];

    char* ws = (char*)d_ws;
    float* weff             = (float*)ws;
    __hip_bfloat16* wexp_bf = (__hip_bfloat16*)(ws + 65536);
    __hip_bfloat16* wmix_bf = (__hip_bfloat16*)(ws + 65536 + 655360);
    const size_t head = 1 << 20;

    const size_t xe_per = (size_t)NEXP * HW * 2;   // 10 MB
    const size_t mg_per = (size_t)C2 * HW * 2;     // 2 MB
    const size_t per_b = xe_per + mg_per;          // 12 MB

    int g = 1;
    if (ws_size > head + per_b) {
        size_t fit = (ws_size - head) / per_b;
        g = (int)(fit < NB ? fit : NB);
        if (g < 1) g = 1;
    }

    char* p = ws + head;
    __hip_bfloat16* xexp   = (__hip_bfloat16*)p; p += (size_t)g * xe_per;
    __hip_bfloat16* merged = (__hip_bfloat16*)p;

    weff_kernel<<<(NK * C2 * 9 + 255) / 256, 256, 0, stream>>>(w_path, weff);
    cvt_bf16_kernel<<<(NEXP * C1 + 255) / 256, 256, 0, stream>>>(w_expand, wexp_bf, NEXP * C1);
    cvt_bf16_kernel<<<(C2 * C2 + 255) / 256, 256, 0, stream>>>(w_mix, wmix_bf, C2 * C2);

    for (int b0 = 0; b0 < NB; b0 += g) {
        int gb = (NB - b0) < g ? (NB - b0) : g;
        // expand (frozen R13/R16 config): NCH=4, plain grid, short4 epilogue
        nstream_gemm_kernel<4, true, true><<<dim3(HW / 256, NEXP / 256, gb), 512, 0, stream>>>(
            wexp_bf, x, xexp,
            (long)C1 * HW, (long)NEXP * HW, b0, 0,
            nullptr, nullptr, nullptr, nullptr);
        // shift_dw v3 (R16-proven): 1 block per (c, z), full plane
        shift_dw_kernel<<<dim3(C2, gb), 512, 0, stream>>>(xexp, weff, merged);
        // mix: NCH=2, LDS-staged fp32 epilogue
        nstream_gemm_kernel<2, false, false><<<dim3(HW / 128, 1, gb), 512, 0, stream>>>(
            wmix_bf, merged, d_out,
            (long)C2 * HW, (long)C2 * HW, 0, b0,
            bn_gamma, bn_beta, bn_mean, bn_var);
    }
}